// Round 1
// baseline (1984.359 us; speedup 1.0000x reference)
//
#include <hip/hip_runtime.h>
#include <cstdint>
#include <cstddef>

#define N_NODES_C 50000
#define N_EDGES_C 1600000

// ---- workspace layout ----
// [0, E*4)              : logits (E floats)
// [E*4, E*4+4)          : maxkey (uint, order-preserving float key)
// [E*4+4, E*4+8)        : sumexp (float)
// [E*4+256, +N*64*4)    : agg (N x 64 floats)
static const size_t LOGITS_OFF = 0;
static const size_t SCAL_OFF   = (size_t)N_EDGES_C * 4;
static const size_t AGG_OFF    = SCAL_OFF + 256;

__device__ __forceinline__ float swish_(float v) {
    return v / (1.0f + __expf(-v));
}

// order-preserving float->uint key for atomicMax
__device__ __forceinline__ unsigned int fkey_(float f) {
    unsigned int u = __float_as_uint(f);
    return (u & 0x80000000u) ? ~u : (u | 0x80000000u);
}
__device__ __forceinline__ float funkey_(unsigned int k) {
    unsigned int u = (k & 0x80000000u) ? (k ^ 0x80000000u) : ~k;
    return __uint_as_float(u);
}

// accumulate d[j] += sum over KK*4 input features (float4 source) times W rows
template<int KK>
__device__ __forceinline__ void accum_rows(float (&d)[64],
                                           const float4* __restrict__ src,
                                           const float* __restrict__ W,
                                           int wbase) {
    for (int kk = 0; kk < KK; ++kk) {
        float4 x = src[kk];
        const float* w0 = W + (size_t)(wbase + kk * 4) * 64;
        #pragma unroll
        for (int j = 0; j < 64; ++j) {
            float a = d[j];
            a = fmaf(x.x, w0[j],       a);
            a = fmaf(x.y, w0[64 + j],  a);
            a = fmaf(x.z, w0[128 + j], a);
            a = fmaf(x.w, w0[192 + j], a);
            d[j] = a;
        }
    }
}

// ---- K1: attention logits + global max ----
__global__ __launch_bounds__(256) void k_att(
    const float* __restrict__ node, const float* __restrict__ edgef,
    const int* __restrict__ senders, const int* __restrict__ receivers,
    const float* __restrict__ Wa1, const float* __restrict__ ba1,
    const float* __restrict__ Wa2, const float* __restrict__ ba2,
    float* __restrict__ logits, unsigned int* __restrict__ maxkey)
{
    const int e = blockIdx.x * 256 + threadIdx.x;   // grid exact: E/256
    const int s = senders[e];
    const int r = receivers[e];

    float d[64];
    #pragma unroll
    for (int j = 0; j < 64; ++j) d[j] = ba1[j];

    const float4* ns = reinterpret_cast<const float4*>(node + (size_t)s * 64);
    const float4* nr = reinterpret_cast<const float4*>(node + (size_t)r * 64);
    const float4* ef = reinterpret_cast<const float4*>(edgef + (size_t)e * 32);
    accum_rows<16>(d, ns, Wa1, 0);
    accum_rows<16>(d, nr, Wa1, 64);
    accum_rows<8>(d, ef, Wa1, 128);

    float logit = ba2[0];
    #pragma unroll
    for (int j = 0; j < 64; ++j)
        logit = fmaf(swish_(d[j]), Wa2[j], logit);
    logits[e] = logit;

    // block max -> atomicMax
    float m = logit;
    #pragma unroll
    for (int off = 32; off; off >>= 1) m = fmaxf(m, __shfl_down(m, off));
    __shared__ float wmax[4];
    if ((threadIdx.x & 63) == 0) wmax[threadIdx.x >> 6] = m;
    __syncthreads();
    if (threadIdx.x == 0) {
        m = fmaxf(fmaxf(wmax[0], wmax[1]), fmaxf(wmax[2], wmax[3]));
        atomicMax(maxkey, fkey_(m));
    }
}

// ---- K2: sum of exp(l - M) ----
__global__ __launch_bounds__(256) void k_sumexp(
    const float* __restrict__ logits, const unsigned int* __restrict__ maxkey,
    float* __restrict__ sumexp)
{
    const float M = funkey_(*maxkey);
    float s = 0.0f;
    for (int e = blockIdx.x * 256 + threadIdx.x; e < N_EDGES_C; e += gridDim.x * 256)
        s += __expf(logits[e] - M);
    #pragma unroll
    for (int off = 32; off; off >>= 1) s += __shfl_down(s, off);
    __shared__ float wsum[4];
    if ((threadIdx.x & 63) == 0) wsum[threadIdx.x >> 6] = s;
    __syncthreads();
    if (threadIdx.x == 0)
        atomicAdd(sumexp, wsum[0] + wsum[1] + wsum[2] + wsum[3]);
}

// ---- K3: message MLP + softmax scale + segmented scatter ----
__global__ __launch_bounds__(256) void k_msg(
    const float* __restrict__ node, const float* __restrict__ edgef,
    const int* __restrict__ senders, const int* __restrict__ receivers,
    const float* __restrict__ W1, const float* __restrict__ b1,
    const float* __restrict__ W2, const float* __restrict__ b2,
    const float* __restrict__ logits, const unsigned int* __restrict__ maxkey,
    const float* __restrict__ sumexp, float* __restrict__ agg)
{
    __shared__ float m_lds[256 * 64];   // 64KB exactly, XOR-swizzled columns
    const int tid = threadIdx.x;
    const int e = blockIdx.x * 256 + tid;
    const int s = senders[e];
    const int r_ = receivers[e];
    (void)r_;

    const float M = funkey_(*maxkey);
    const float invZ = 1.0f / sumexp[0];
    const float w = __expf(logits[e] - M) * invZ;

    float d[64];
    #pragma unroll
    for (int j = 0; j < 64; ++j) d[j] = b1[j];

    const float4* ns = reinterpret_cast<const float4*>(node + (size_t)s * 64);
    const float4* nr = reinterpret_cast<const float4*>(node + (size_t)receivers[e] * 64);
    const float4* ef = reinterpret_cast<const float4*>(edgef + (size_t)e * 32);
    accum_rows<16>(d, ns, W1, 0);
    accum_rows<16>(d, nr, W1, 64);
    accum_rows<8>(d, ef, W1, 128);

    // h = w * swish(d)   (fold softmax weight into hidden)
    #pragma unroll
    for (int t = 0; t < 64; ++t) d[t] = w * swish_(d[t]);

    // second GEMM: m[j] = w*b2[j] + sum_t h[t]*W2[t][j]; write swizzled to LDS
    const int sw = tid & 63;
    for (int j = 0; j < 64; ++j) {          // j uniform -> scalar weight loads
        float acc = w * b2[j];
        #pragma unroll
        for (int t = 0; t < 64; ++t)
            acc = fmaf(d[t], W2[t * 64 + j], acc);
        m_lds[tid * 64 + (j ^ sw)] = acc;
    }
    __syncthreads();

    // phase B: wave w handles 64-edge window, lane = unit j. receivers sorted ->
    // accumulate runs of equal r, one coalesced wave-atomic per run.
    const int j = tid & 63;
    const int base = (tid >> 6) * 64;
    const int rbase = blockIdx.x * 256 + base;
    float acc = 0.0f;
    int cur = receivers[rbase];
    for (int i = 0; i < 64; ++i) {
        int rr = receivers[rbase + i];      // uniform scalar load
        if (rr != cur) {
            atomicAdd(&agg[(size_t)cur * 64 + j], acc);
            acc = 0.0f;
            cur = rr;
        }
        int row = base + i;
        acc += m_lds[row * 64 + (j ^ (row & 63))];
    }
    atomicAdd(&agg[(size_t)cur * 64 + j], acc);
}

// ---- K4: update MLP, wave per node (lane = unit) ----
__global__ __launch_bounds__(256) void k_upd(
    const float* __restrict__ node, const float* __restrict__ agg,
    const float* __restrict__ Wu1, const float* __restrict__ bu1,
    const float* __restrict__ Wu2, const float* __restrict__ bu2,
    float* __restrict__ out)
{
    const int tid = threadIdx.x;
    const int j = tid & 63;
    const int nl = tid >> 6;                 // wave index in block, uniform per wave
    const int n = blockIdx.x * 4 + nl;       // grid exact: N/4

    __shared__ float h_lds[4][65];

    const float* np_ = node + (size_t)n * 64;   // uniform per wave -> scalar loads
    const float* ap_ = agg + (size_t)n * 64;

    float dacc = bu1[j];
    #pragma unroll 8
    for (int k = 0; k < 64; ++k)
        dacc = fmaf(np_[k], Wu1[k * 64 + j], dacc);          // coalesced weight load
    #pragma unroll 8
    for (int k = 0; k < 64; ++k)
        dacc = fmaf(ap_[k], Wu1[(64 + k) * 64 + j], dacc);

    h_lds[nl][j] = swish_(dacc);
    __syncthreads();

    float o = bu2[j];
    #pragma unroll 8
    for (int t = 0; t < 64; ++t)
        o = fmaf(h_lds[nl][t], Wu2[t * 64 + j], o);
    out[(size_t)n * 64 + j] = o;
}

extern "C" void kernel_launch(void* const* d_in, const int* in_sizes, int n_in,
                              void* d_out, int out_size, void* d_ws, size_t ws_size,
                              hipStream_t stream)
{
    const float* node      = (const float*)d_in[0];
    const float* edgef     = (const float*)d_in[1];
    const int*   senders   = (const int*)d_in[2];
    const int*   receivers = (const int*)d_in[3];
    const float* W1  = (const float*)d_in[4];
    const float* b1  = (const float*)d_in[5];
    const float* W2  = (const float*)d_in[6];
    const float* b2  = (const float*)d_in[7];
    const float* Wa1 = (const float*)d_in[8];
    const float* ba1 = (const float*)d_in[9];
    const float* Wa2 = (const float*)d_in[10];
    const float* ba2 = (const float*)d_in[11];
    const float* Wu1 = (const float*)d_in[12];
    const float* bu1 = (const float*)d_in[13];
    const float* Wu2 = (const float*)d_in[14];
    const float* bu2 = (const float*)d_in[15];
    float* out = (float*)d_out;

    char* ws = (char*)d_ws;
    float*        logits = (float*)(ws + LOGITS_OFF);
    unsigned int* maxkey = (unsigned int*)(ws + SCAL_OFF);
    float*        sumexp = (float*)(ws + SCAL_OFF + 4);
    float*        agg    = (float*)(ws + AGG_OFF);

    // zero scalars + agg (ws is poisoned 0xAA before every launch)
    hipMemsetAsync(ws + SCAL_OFF, 0, 256 + (size_t)N_NODES_C * 64 * 4, stream);

    k_att<<<N_EDGES_C / 256, 256, 0, stream>>>(node, edgef, senders, receivers,
                                               Wa1, ba1, Wa2, ba2, logits, maxkey);
    k_sumexp<<<2048, 256, 0, stream>>>(logits, maxkey, sumexp);
    k_msg<<<N_EDGES_C / 256, 256, 0, stream>>>(node, edgef, senders, receivers,
                                               W1, b1, W2, b2, logits, maxkey, sumexp, agg);
    k_upd<<<N_NODES_C / 4, 256, 0, stream>>>(node, agg, Wu1, bu1, Wu2, bu2, out);
}

// Round 2
// 887.748 us; speedup vs baseline: 2.2353x; 2.2353x over previous
//
#include <hip/hip_runtime.h>
#include <cstdint>
#include <cstddef>

#define N_NODES_C 50000
#define N_EDGES_C 1600000

// ---- workspace layout ----
static const size_t LOGITS_OFF = 0;
static const size_t SCAL_OFF   = (size_t)N_EDGES_C * 4;
static const size_t AGG_OFF    = SCAL_OFF + 256;

typedef __attribute__((ext_vector_type(8)))  short bf16x8;
typedef __attribute__((ext_vector_type(16))) float f32x16;

__device__ __forceinline__ float swish_(float v) { return v / (1.0f + __expf(-v)); }

__device__ __forceinline__ unsigned int fkey_(float f) {
    unsigned int u = __float_as_uint(f);
    return (u & 0x80000000u) ? ~u : (u | 0x80000000u);
}
__device__ __forceinline__ float funkey_(unsigned int k) {
    unsigned int u = (k & 0x80000000u) ? (k ^ 0x80000000u) : ~k;
    return __uint_as_float(u);
}
// fp32 -> bf16 bits, round-to-nearest-even
__device__ __forceinline__ unsigned short f2bf(float f) {
    unsigned int u = __float_as_uint(f);
    return (unsigned short)((u + 0x7FFFu + ((u >> 16) & 1u)) >> 16);
}
__device__ __forceinline__ unsigned int pack2(float a, float b) {
    return (unsigned int)f2bf(a) | ((unsigned int)f2bf(b) << 16);
}

// stage msg_in tile (128 edges x 160 feats) as bf16 into A[128][168]
__device__ __forceinline__ void stage_msg_in(unsigned short* A,
    const float* __restrict__ node, const float* __restrict__ edgef,
    const int* __restrict__ senders, const int* __restrict__ receivers,
    int e0, int tid)
{
    const int el = tid & 127, part = tid >> 7;
    const int e = e0 + el;
    const int nidx = part ? receivers[e] : senders[e];
    const float4* row = (const float4*)(node + (size_t)nidx * 64);
    unsigned short* arow = A + el * 168 + part * 64;
    #pragma unroll
    for (int q = 0; q < 8; ++q) {
        float4 x = row[2 * q], y = row[2 * q + 1];
        uint4 p = { pack2(x.x, x.y), pack2(x.z, x.w), pack2(y.x, y.y), pack2(y.z, y.w) };
        *(uint4*)(arow + q * 8) = p;
    }
    const float4* ef = (const float4*)(edgef + (size_t)e * 32) + part * 4;
    unsigned short* erow = A + el * 168 + 128 + part * 16;
    #pragma unroll
    for (int q = 0; q < 2; ++q) {
        float4 x = ef[2 * q], y = ef[2 * q + 1];
        uint4 p = { pack2(x.x, x.y), pack2(x.z, x.w), pack2(y.x, y.y), pack2(y.z, y.w) };
        *(uint4*)(erow + q * 8) = p;
    }
}

// stage W (K x 64, row-major) transposed as bf16 into Wt[64][LW]
__device__ __forceinline__ void stage_Wt(unsigned short* Wt,
    const float* __restrict__ W, int K, int LW, int tid)
{
    const int pairs = K * 32;           // (K/2)*64
    for (int p = tid; p < pairs; p += 256) {
        int n = p & 63, k2 = (p >> 6) << 1;
        float a = W[(size_t)k2 * 64 + n];
        float b = W[(size_t)(k2 + 1) * 64 + n];
        *(unsigned int*)(Wt + n * LW + k2) = pack2(a, b);
    }
}

// ---- K1: attention logits + global max (MFMA) ----
__global__ __launch_bounds__(256) void k_att(
    const float* __restrict__ node, const float* __restrict__ edgef,
    const int* __restrict__ senders, const int* __restrict__ receivers,
    const float* __restrict__ Wa1, const float* __restrict__ ba1,
    const float* __restrict__ Wa2, const float* __restrict__ ba2,
    float* __restrict__ logits, unsigned int* __restrict__ maxkey)
{
    __shared__ unsigned short A[128 * 168];
    __shared__ unsigned short Wt[64 * 168];
    __shared__ float bmax[4];
    const int tid = threadIdx.x;
    const int e0 = blockIdx.x * 128;

    stage_Wt(Wt, Wa1, 160, 168, tid);
    stage_msg_in(A, node, edgef, senders, receivers, e0, tid);
    __syncthreads();

    const int lane = tid & 63, w = tid >> 6;
    const int lr = lane & 31, kh = (lane >> 5) * 8, hi = lane >> 5;

    f32x16 c0, c1;
    #pragma unroll
    for (int j = 0; j < 16; ++j) { c0[j] = 0.0f; c1[j] = 0.0f; }

    const unsigned short* ap  = A  + (w * 32 + lr) * 168 + kh;
    const unsigned short* b0p = Wt + lr * 168 + kh;
    const unsigned short* b1p = Wt + (32 + lr) * 168 + kh;
    #pragma unroll
    for (int kk = 0; kk < 10; ++kk) {
        bf16x8 a  = *(const bf16x8*)(ap  + kk * 16);
        bf16x8 b0 = *(const bf16x8*)(b0p + kk * 16);
        bf16x8 b1 = *(const bf16x8*)(b1p + kk * 16);
        c0 = __builtin_amdgcn_mfma_f32_32x32x16_bf16(a, b0, c0, 0, 0, 0);
        c1 = __builtin_amdgcn_mfma_f32_32x32x16_bf16(a, b1, c1, 0, 0, 0);
    }

    // epilogue: logit_e = ba2 + sum_j swish(h[e][j]) * Wa2[j]
    const float bb0 = ba1[lr], bb1 = ba1[32 + lr];
    const float wa0 = Wa2[lr], wa1v = Wa2[32 + lr];
    const float ba2v = ba2[0];
    const int ew = e0 + w * 32;
    float mymax = -3.4e38f, mylogit = 0.0f;
    #pragma unroll
    for (int t = 0; t < 16; ++t) {
        float v = swish_(c0[t] + bb0) * wa0 + swish_(c1[t] + bb1) * wa1v;
        v += __shfl_xor(v, 1);  v += __shfl_xor(v, 2);  v += __shfl_xor(v, 4);
        v += __shfl_xor(v, 8);  v += __shfl_xor(v, 16);
        float logit = v + ba2v;
        if (lr == t) mylogit = logit;
        mymax = fmaxf(mymax, logit);
    }
    if (lr < 16) logits[ew + (lr & 3) + 8 * (lr >> 2) + 4 * hi] = mylogit;

    mymax = fmaxf(mymax, __shfl_xor(mymax, 32));
    if (lane == 0) bmax[w] = mymax;
    __syncthreads();
    if (tid == 0)
        atomicMax(maxkey, fkey_(fmaxf(fmaxf(bmax[0], bmax[1]), fmaxf(bmax[2], bmax[3]))));
}

// ---- K2: sum of exp(l - M) ----
__global__ __launch_bounds__(256) void k_sumexp(
    const float* __restrict__ logits, const unsigned int* __restrict__ maxkey,
    float* __restrict__ sumexp)
{
    const float M = funkey_(*maxkey);
    float s = 0.0f;
    for (int e = blockIdx.x * 256 + threadIdx.x; e < N_EDGES_C; e += gridDim.x * 256)
        s += __expf(logits[e] - M);
    #pragma unroll
    for (int off = 32; off; off >>= 1) s += __shfl_down(s, off);
    __shared__ float wsum[4];
    if ((threadIdx.x & 63) == 0) wsum[threadIdx.x >> 6] = s;
    __syncthreads();
    if (threadIdx.x == 0)
        atomicAdd(sumexp, wsum[0] + wsum[1] + wsum[2] + wsum[3]);
}

// ---- K3: message MLP (2x MFMA) + softmax scale + segmented scatter ----
__global__ __launch_bounds__(256) void k_msg(
    const float* __restrict__ node, const float* __restrict__ edgef,
    const int* __restrict__ senders, const int* __restrict__ receivers,
    const float* __restrict__ W1, const float* __restrict__ b1,
    const float* __restrict__ W2, const float* __restrict__ b2,
    const float* __restrict__ logits, const unsigned int* __restrict__ maxkey,
    const float* __restrict__ sumexp, float* __restrict__ agg)
{
    __shared__ unsigned short A[128 * 168];
    __shared__ unsigned short W1t[64 * 168];
    __shared__ unsigned short W2t[64 * 72];
    const int tid = threadIdx.x;
    const int e0 = blockIdx.x * 128;

    stage_Wt(W1t, W1, 160, 168, tid);
    stage_Wt(W2t, W2, 64, 72, tid);
    stage_msg_in(A, node, edgef, senders, receivers, e0, tid);
    __syncthreads();

    const int lane = tid & 63, w = tid >> 6;
    const int lr = lane & 31, kh = (lane >> 5) * 8, hi = lane >> 5;

    // GEMM1: msg_in @ W1
    f32x16 c0, c1;
    #pragma unroll
    for (int j = 0; j < 16; ++j) { c0[j] = 0.0f; c1[j] = 0.0f; }
    const unsigned short* ap  = A   + (w * 32 + lr) * 168 + kh;
    const unsigned short* b0p = W1t + lr * 168 + kh;
    const unsigned short* b1p = W1t + (32 + lr) * 168 + kh;
    #pragma unroll
    for (int kk = 0; kk < 10; ++kk) {
        bf16x8 a  = *(const bf16x8*)(ap  + kk * 16);
        bf16x8 b0 = *(const bf16x8*)(b0p + kk * 16);
        bf16x8 b1 = *(const bf16x8*)(b1p + kk * 16);
        c0 = __builtin_amdgcn_mfma_f32_32x32x16_bf16(a, b0, c0, 0, 0, 0);
        c1 = __builtin_amdgcn_mfma_f32_32x32x16_bf16(a, b1, c1, 0, 0, 0);
    }

    // H = bf16(swish(c + b1)) into wave-private region of A, layout [32][72]
    const float b1j0 = b1[lr], b1j1 = b1[32 + lr];
    unsigned short* H = A + (w * 32) * 168;
    #pragma unroll
    for (int t = 0; t < 16; ++t) {
        int r = (t & 3) + 8 * (t >> 2) + 4 * hi;
        H[r * 72 + lr]      = f2bf(swish_(c0[t] + b1j0));
        H[r * 72 + 32 + lr] = f2bf(swish_(c1[t] + b1j1));
    }

    // GEMM2: H @ W2 (wave-private LDS, DS ops in-order -> no barrier)
    f32x16 d0, d1;
    #pragma unroll
    for (int j = 0; j < 16; ++j) { d0[j] = 0.0f; d1[j] = 0.0f; }
    const unsigned short* hp  = H   + lr * 72 + kh;
    const unsigned short* w20 = W2t + lr * 72 + kh;
    const unsigned short* w21 = W2t + (32 + lr) * 72 + kh;
    #pragma unroll
    for (int kk = 0; kk < 4; ++kk) {
        bf16x8 a  = *(const bf16x8*)(hp  + kk * 16);
        bf16x8 b0 = *(const bf16x8*)(w20 + kk * 16);
        bf16x8 b1f = *(const bf16x8*)(w21 + kk * 16);
        d0 = __builtin_amdgcn_mfma_f32_32x32x16_bf16(a, b0,  d0, 0, 0, 0);
        d1 = __builtin_amdgcn_mfma_f32_32x32x16_bf16(a, b1f, d1, 0, 0, 0);
    }

    // attention weights (softmax over all edges) + bias, folded into messages
    const float M = funkey_(*maxkey);
    const float invZ = 1.0f / sumexp[0];
    const int ew = e0 + w * 32;
    float w_l = __expf(logits[ew + lr] - M) * invZ;   // lane r holds weight of edge ew+r
    const float b2j0 = b2[lr], b2j1 = b2[32 + lr];
    float m0[16], m1[16];
    #pragma unroll
    for (int t = 0; t < 16; ++t) {
        int r = (t & 3) + 8 * (t >> 2) + 4 * hi;
        float wv = __shfl(w_l, r);
        m0[t] = (d0[t] + b2j0) * wv;
        m1[t] = (d1[t] + b2j1) * wv;
    }

    // segmented scatter: receivers sorted -> accumulate runs, coalesced atomics (lane = unit)
    const int ews = __builtin_amdgcn_readfirstlane(ew);
    float acc = 0.0f;
    int cur = receivers[ews];
    #pragma unroll
    for (int i = 0; i < 32; ++i) {
        int t = (i & 3) + 4 * (i >> 3);
        int sel = (i >> 2) & 1;
        float am = __shfl_xor(m0[t], 32);
        float bm = __shfl_xor(m1[t], 32);
        float low  = sel ? am : m0[t];
        float high = sel ? m1[t] : bm;
        float val = (lane < 32) ? low : high;
        int rr = receivers[ews + i];
        if (rr != cur) {
            atomicAdd(&agg[(size_t)cur * 64 + lane], acc);
            acc = 0.0f; cur = rr;
        }
        acc += val;
    }
    atomicAdd(&agg[(size_t)cur * 64 + lane], acc);
}

// ---- K4: update MLP, wave per node (lane = unit) ----
__global__ __launch_bounds__(256) void k_upd(
    const float* __restrict__ node, const float* __restrict__ agg,
    const float* __restrict__ Wu1, const float* __restrict__ bu1,
    const float* __restrict__ Wu2, const float* __restrict__ bu2,
    float* __restrict__ out)
{
    const int tid = threadIdx.x;
    const int j = tid & 63;
    const int nl = tid >> 6;
    const int n = blockIdx.x * 4 + nl;

    __shared__ float h_lds[4][65];

    const float* np_ = node + (size_t)n * 64;
    const float* ap_ = agg + (size_t)n * 64;

    float dacc = bu1[j];
    #pragma unroll 8
    for (int k = 0; k < 64; ++k)
        dacc = fmaf(np_[k], Wu1[k * 64 + j], dacc);
    #pragma unroll 8
    for (int k = 0; k < 64; ++k)
        dacc = fmaf(ap_[k], Wu1[(64 + k) * 64 + j], dacc);

    h_lds[nl][j] = swish_(dacc);
    __syncthreads();

    float o = bu2[j];
    #pragma unroll 8
    for (int t = 0; t < 64; ++t)
        o = fmaf(h_lds[nl][t], Wu2[t * 64 + j], o);
    out[(size_t)n * 64 + j] = o;
}

extern "C" void kernel_launch(void* const* d_in, const int* in_sizes, int n_in,
                              void* d_out, int out_size, void* d_ws, size_t ws_size,
                              hipStream_t stream)
{
    const float* node      = (const float*)d_in[0];
    const float* edgef     = (const float*)d_in[1];
    const int*   senders   = (const int*)d_in[2];
    const int*   receivers = (const int*)d_in[3];
    const float* W1  = (const float*)d_in[4];
    const float* b1  = (const float*)d_in[5];
    const float* W2  = (const float*)d_in[6];
    const float* b2  = (const float*)d_in[7];
    const float* Wa1 = (const float*)d_in[8];
    const float* ba1 = (const float*)d_in[9];
    const float* Wa2 = (const float*)d_in[10];
    const float* ba2 = (const float*)d_in[11];
    const float* Wu1 = (const float*)d_in[12];
    const float* bu1 = (const float*)d_in[13];
    const float* Wu2 = (const float*)d_in[14];
    const float* bu2 = (const float*)d_in[15];
    float* out = (float*)d_out;

    char* ws = (char*)d_ws;
    float*        logits = (float*)(ws + LOGITS_OFF);
    unsigned int* maxkey = (unsigned int*)(ws + SCAL_OFF);
    float*        sumexp = (float*)(ws + SCAL_OFF + 4);
    float*        agg    = (float*)(ws + AGG_OFF);

    hipMemsetAsync(ws + SCAL_OFF, 0, 256 + (size_t)N_NODES_C * 64 * 4, stream);

    k_att<<<N_EDGES_C / 128, 256, 0, stream>>>(node, edgef, senders, receivers,
                                               Wa1, ba1, Wa2, ba2, logits, maxkey);
    k_sumexp<<<2048, 256, 0, stream>>>(logits, maxkey, sumexp);
    k_msg<<<N_EDGES_C / 128, 256, 0, stream>>>(node, edgef, senders, receivers,
                                               W1, b1, W2, b2, logits, maxkey, sumexp, agg);
    k_upd<<<N_NODES_C / 4, 256, 0, stream>>>(node, agg, Wu1, bu1, Wu2, bu2, out);
}

// Round 3
// 629.042 us; speedup vs baseline: 3.1546x; 1.4113x over previous
//
#include <hip/hip_runtime.h>
#include <cstdint>
#include <cstddef>

#define N_NODES_C 50000
#define N_EDGES_C 1600000

typedef __attribute__((ext_vector_type(8)))  short bf16x8;
typedef __attribute__((ext_vector_type(16))) float f32x16;
typedef unsigned short ushort_t;

// ---- workspace layout ----
// [0,256): expsum scalar; [256, +12.8M): agg fp32; then node_bf; then weight images
static const size_t AGG_OFF   = 256;
static const size_t NB_OFF    = 256 + (size_t)N_NODES_C * 64 * 4;          // 12800256
static const size_t WIMG_OFF  = NB_OFF + (size_t)N_NODES_C * 64 * 2;       // +6.4MB
static const size_t WUIMG_OFF = WIMG_OFF + 52224;                          // Wm(21504)+Wa(21504)+W2t(9216)

__device__ __forceinline__ float swish_(float v) { return v / (1.0f + __expf(-v)); }

__device__ __forceinline__ unsigned short f2bf(float f) {
    unsigned int u = __float_as_uint(f);
    return (unsigned short)((u + 0x7FFFu + ((u >> 16) & 1u)) >> 16);
}
__device__ __forceinline__ unsigned int pack2(float a, float b) {
    return (unsigned int)f2bf(a) | ((unsigned int)f2bf(b) << 16);
}

// async global->LDS, 16B per lane (dest: wave-uniform base + lane*16)
typedef __attribute__((address_space(3))) unsigned int lds_u32_t;
typedef const __attribute__((address_space(1))) unsigned int glb_u32_t;
__device__ __forceinline__ void glds16(const void* g, void* l) {
    __builtin_amdgcn_global_load_lds((glb_u32_t*)g, (lds_u32_t*)l, 16, 0, 0);
}

// ---- prep: node features fp32 -> bf16 image ----
__global__ __launch_bounds__(256) void k_prep_node(const float* __restrict__ node,
                                                   ushort_t* __restrict__ node_bf)
{
    int i = blockIdx.x * 256 + threadIdx.x;
    if (i >= N_NODES_C * 64 / 8) return;
    const float4* s = (const float4*)node + (size_t)i * 2;
    float4 a = s[0], b = s[1];
    uint4 p = { pack2(a.x,a.y), pack2(a.z,a.w), pack2(b.x,b.y), pack2(b.z,b.w) };
    ((uint4*)node_bf)[i] = p;
}

// ---- prep: transposed bf16 weight images (exact LDS layouts) ----
__global__ __launch_bounds__(256) void k_prep_w(
    const float* __restrict__ W1, const float* __restrict__ Wa1,
    const float* __restrict__ W2, const float* __restrict__ Wu1,
    const float* __restrict__ Wu2,
    ushort_t* __restrict__ wm, ushort_t* __restrict__ wa, ushort_t* __restrict__ w2t,
    ushort_t* __restrict__ wu1t, ushort_t* __restrict__ wu2t)
{
    int b = blockIdx.x, t = threadIdx.x;
    const float* W; ushort_t* dst; int K, LP, p;
    if (b < 21)      { W = W1;  dst = wm;   K = 160; LP = 84; p = b * 256 + t; }
    else if (b < 42) { W = Wa1; dst = wa;   K = 160; LP = 84; p = (b-21)*256 + t; }
    else if (b < 51) { W = W2;  dst = w2t;  K = 64;  LP = 36; p = (b-42)*256 + t; }
    else if (b < 68) { W = Wu1; dst = wu1t; K = 128; LP = 68; p = (b-51)*256 + t; }
    else             { W = Wu2; dst = wu2t; K = 64;  LP = 36; p = (b-68)*256 + t; }
    int n = p / LP; int k2 = (p - n * LP) * 2;
    if (n >= 64) return;
    float a = (k2     < K) ? W[(size_t)k2 * 64 + n]       : 0.f;
    float c = (k2 + 1 < K) ? W[(size_t)(k2 + 1) * 64 + n] : 0.f;
    *(unsigned int*)(dst + (size_t)n * LP * 2 + k2) = pack2(a, c);
}

// ---- fused edge kernel: att logits + exp + message MLP + scaled scatter ----
__global__ __launch_bounds__(512, 2) void k_edge(
    const ushort_t* __restrict__ node_bf, const float* __restrict__ edgef,
    const int* __restrict__ senders, const int* __restrict__ receivers,
    const ushort_t* __restrict__ wimg,
    const float* __restrict__ b1, const float* __restrict__ ba1,
    const float* __restrict__ Wa2, const float* __restrict__ ba2,
    const float* __restrict__ b2,
    float* __restrict__ expsum, float* __restrict__ agg)
{
    __shared__ ushort_t As[256 * 64];     // sender rows, chunk-swizzled
    __shared__ ushort_t Ar[256 * 64];     // receiver rows
    __shared__ ushort_t Ae[256 * 32];     // edge feats
    __shared__ ushort_t WmWa[21504];      // Wm[64][168] @0, Wa @10752; later H[256][72]
    __shared__ ushort_t W2s[64 * 72];
    __shared__ float psum[8];

    const int tid = threadIdx.x;
    const int e0 = blockIdx.x * 256;

    // weights (linear copy of prebuilt images)
    for (int c = tid; c < 2688; c += 512)
        glds16((const char*)wimg + c * 16, (char*)WmWa + c * 16);
    for (int c = tid; c < 576; c += 512)
        glds16((const char*)wimg + 43008 + c * 16, (char*)W2s + c * 16);
    // gathered A rows: LDS chunk c holds source chunk c^(row&7) (inverse-swz source)
    #pragma unroll
    for (int i = 0; i < 4; ++i) {
        int cg = tid + i * 512;
        int row = cg >> 3, c = cg & 7;
        glds16(node_bf + (size_t)senders[e0 + row] * 64 + ((c ^ (row & 7)) << 3),
               (char*)As + cg * 16);
    }
    #pragma unroll
    for (int i = 0; i < 4; ++i) {
        int cg = tid + i * 512;
        int row = cg >> 3, c = cg & 7;
        glds16(node_bf + (size_t)receivers[e0 + row] * 64 + ((c ^ (row & 7)) << 3),
               (char*)Ar + cg * 16);
    }
    // edge feats: fp32->bf16 in VALU (overlaps in-flight async loads)
    {
        int row = tid >> 1, hf = tid & 1;
        const float4* ef = (const float4*)(edgef + (size_t)(e0 + row) * 32 + hf * 16);
        float4 x0 = ef[0], x1 = ef[1], x2 = ef[2], x3 = ef[3];
        uint4 p0 = { pack2(x0.x,x0.y), pack2(x0.z,x0.w), pack2(x1.x,x1.y), pack2(x1.z,x1.w) };
        uint4 p1 = { pack2(x2.x,x2.y), pack2(x2.z,x2.w), pack2(x3.x,x3.y), pack2(x3.z,x3.w) };
        int r3 = row & 3;
        *(uint4*)(Ae + row * 32 + (((2*hf)   ^ r3) << 3)) = p0;
        *(uint4*)(Ae + row * 32 + (((2*hf+1) ^ r3) << 3)) = p1;
    }
    __syncthreads();

    const int lane = tid & 63, w = tid >> 6;
    const int lr = lane & 31, hi = lane >> 5, kh = hi * 8;
    const int row_a = w * 32 + lr;
    const int r7 = lr & 7, r3 = lr & 3;

    f32x16 ca0, ca1, cm0, cm1;
    #pragma unroll
    for (int j = 0; j < 16; ++j) { ca0[j]=0.f; ca1[j]=0.f; cm0[j]=0.f; cm1[j]=0.f; }

    const ushort_t* asr = As + row_a * 64;
    const ushort_t* arr = Ar + row_a * 64;
    const ushort_t* aer = Ae + row_a * 32;
    const ushort_t* wm0 = WmWa + lr * 168 + kh;
    const ushort_t* wm1 = WmWa + (32 + lr) * 168 + kh;
    const ushort_t* wa0 = WmWa + 10752 + lr * 168 + kh;
    const ushort_t* wa1 = WmWa + 10752 + (32 + lr) * 168 + kh;

    #pragma unroll
    for (int kk = 0; kk < 4; ++kk) {       // k 0..63: sender
        bf16x8 a = *(const bf16x8*)(asr + (((2*kk + hi) ^ r7) << 3));
        cm0 = __builtin_amdgcn_mfma_f32_32x32x16_bf16(a, *(const bf16x8*)(wm0 + kk*16), cm0, 0,0,0);
        cm1 = __builtin_amdgcn_mfma_f32_32x32x16_bf16(a, *(const bf16x8*)(wm1 + kk*16), cm1, 0,0,0);
        ca0 = __builtin_amdgcn_mfma_f32_32x32x16_bf16(a, *(const bf16x8*)(wa0 + kk*16), ca0, 0,0,0);
        ca1 = __builtin_amdgcn_mfma_f32_32x32x16_bf16(a, *(const bf16x8*)(wa1 + kk*16), ca1, 0,0,0);
    }
    #pragma unroll
    for (int kk = 4; kk < 8; ++kk) {       // k 64..127: receiver
        bf16x8 a = *(const bf16x8*)(arr + (((2*kk - 8 + hi) ^ r7) << 3));
        cm0 = __builtin_amdgcn_mfma_f32_32x32x16_bf16(a, *(const bf16x8*)(wm0 + kk*16), cm0, 0,0,0);
        cm1 = __builtin_amdgcn_mfma_f32_32x32x16_bf16(a, *(const bf16x8*)(wm1 + kk*16), cm1, 0,0,0);
        ca0 = __builtin_amdgcn_mfma_f32_32x32x16_bf16(a, *(const bf16x8*)(wa0 + kk*16), ca0, 0,0,0);
        ca1 = __builtin_amdgcn_mfma_f32_32x32x16_bf16(a, *(const bf16x8*)(wa1 + kk*16), ca1, 0,0,0);
    }
    #pragma unroll
    for (int kk = 8; kk < 10; ++kk) {      // k 128..159: edge feats
        bf16x8 a = *(const bf16x8*)(aer + (((2*kk - 16 + hi) ^ r3) << 3));
        cm0 = __builtin_amdgcn_mfma_f32_32x32x16_bf16(a, *(const bf16x8*)(wm0 + kk*16), cm0, 0,0,0);
        cm1 = __builtin_amdgcn_mfma_f32_32x32x16_bf16(a, *(const bf16x8*)(wm1 + kk*16), cm1, 0,0,0);
        ca0 = __builtin_amdgcn_mfma_f32_32x32x16_bf16(a, *(const bf16x8*)(wa0 + kk*16), ca0, 0,0,0);
        ca1 = __builtin_amdgcn_mfma_f32_32x32x16_bf16(a, *(const bf16x8*)(wa1 + kk*16), ca1, 0,0,0);
    }

    // attention epilogue: p = exp(logit) (unnormalized; M cancels in agg/Z)
    float p;
    {
        const float bb0 = ba1[lr], bb1 = ba1[32 + lr];
        const float wv0 = Wa2[lr], wv1 = Wa2[32 + lr];
        const float bb2 = ba2[0];
        float myl = 0.f;
        #pragma unroll
        for (int t = 0; t < 16; ++t) {
            float v = swish_(ca0[t] + bb0) * wv0 + swish_(ca1[t] + bb1) * wv1;
            v += __shfl_xor(v, 1);  v += __shfl_xor(v, 2);  v += __shfl_xor(v, 4);
            v += __shfl_xor(v, 8);  v += __shfl_xor(v, 16);
            if (lr == t) myl = v + bb2;
        }
        p = (lr < 16) ? __expf(myl) : 0.f;
        float ps = p;
        ps += __shfl_xor(ps, 1);  ps += __shfl_xor(ps, 2);  ps += __shfl_xor(ps, 4);
        ps += __shfl_xor(ps, 8);  ps += __shfl_xor(ps, 16); ps += __shfl_xor(ps, 32);
        if (lane == 0) psum[w] = ps;
    }
    __syncthreads();                       // Wm/Wa reads done; psum ready
    if (tid == 0) {
        float s = 0.f;
        #pragma unroll
        for (int q = 0; q < 8; ++q) s += psum[q];
        atomicAdd(expsum, s);
    }

    // H = bf16(swish(cm + b1)) into WmWa region (H[256][72]); wave-private rows
    const float b10 = b1[lr], b11 = b1[32 + lr];
    ushort_t* H = WmWa;
    #pragma unroll
    for (int t = 0; t < 16; ++t) {
        int r = (t & 3) + 8 * (t >> 2) + 4 * hi;
        int g = (w * 32 + r) * 72;
        H[g + lr]      = f2bf(swish_(cm0[t] + b10));
        H[g + 32 + lr] = f2bf(swish_(cm1[t] + b11));
    }

    // GEMM2: H @ W2 (same-wave in-order DS, no barrier)
    f32x16 d0, d1;
    #pragma unroll
    for (int j = 0; j < 16; ++j) { d0[j] = 0.f; d1[j] = 0.f; }
    const ushort_t* hp = H + row_a * 72 + kh;
    const ushort_t* q0 = W2s + lr * 72 + kh;
    const ushort_t* q1 = W2s + (32 + lr) * 72 + kh;
    #pragma unroll
    for (int kk = 0; kk < 4; ++kk) {
        bf16x8 a = *(const bf16x8*)(hp + kk * 16);
        d0 = __builtin_amdgcn_mfma_f32_32x32x16_bf16(a, *(const bf16x8*)(q0 + kk*16), d0, 0,0,0);
        d1 = __builtin_amdgcn_mfma_f32_32x32x16_bf16(a, *(const bf16x8*)(q1 + kk*16), d1, 0,0,0);
    }

    // scale by exp(logit) and segmented scatter (receivers sorted)
    const float b20 = b2[lr], b21 = b2[32 + lr];
    float m0[16], m1[16];
    #pragma unroll
    for (int t = 0; t < 16; ++t) {
        int r = (t & 3) + 8 * (t >> 2) + 4 * hi;
        int src = ((r & 3) + 4 * (r >> 3)) + 32 * ((r >> 2) & 1);
        float wv = __shfl(p, src);
        m0[t] = (d0[t] + b20) * wv;
        m1[t] = (d1[t] + b21) * wv;
    }
    const int ews = e0 + w * 32;
    float acc = 0.f;
    int cur = receivers[ews];
    #pragma unroll
    for (int i = 0; i < 32; ++i) {
        int t = (i & 3) + 4 * (i >> 3);
        int sel = (i >> 2) & 1;
        float am = __shfl_xor(m0[t], 32);
        float bm = __shfl_xor(m1[t], 32);
        float low  = sel ? am : m0[t];
        float high = sel ? m1[t] : bm;
        float val = (lane < 32) ? low : high;
        int rr = receivers[ews + i];
        if (rr != cur) {
            atomicAdd(&agg[(size_t)cur * 64 + lane], acc);
            acc = 0.f; cur = rr;
        }
        acc += val;
    }
    atomicAdd(&agg[(size_t)cur * 64 + lane], acc);
}

// ---- update MLP (MFMA), 128 nodes/block ----
__global__ __launch_bounds__(256) void k_upd(
    const ushort_t* __restrict__ node_bf, const float* __restrict__ agg,
    const ushort_t* __restrict__ wuimg,
    const float* __restrict__ bu1, const float* __restrict__ bu2,
    const float* __restrict__ expsum, float* __restrict__ out)
{
    __shared__ ushort_t Un[128 * 64];
    __shared__ ushort_t Ua[128 * 64];
    __shared__ ushort_t Wu[13312];        // Wu1t[64][136] @0 (8704), Wu2t[64][72] @8704
    __shared__ ushort_t H2[128 * 72];

    const int tid = threadIdx.x;
    const int n0 = blockIdx.x * 128;

    for (int c = tid; c < 1664; c += 256)
        glds16((const char*)wuimg + c * 16, (char*)Wu + c * 16);
    #pragma unroll
    for (int i = 0; i < 4; ++i) {
        int cg = tid + i * 256;
        int row = cg >> 3, c = cg & 7;
        int n = n0 + row; if (n >= N_NODES_C) n = N_NODES_C - 1;
        glds16(node_bf + (size_t)n * 64 + ((c ^ (row & 7)) << 3), (char*)Un + cg * 16);
    }
    const float invZ = 1.0f / expsum[0];
    {
        int row = tid >> 1, hf = tid & 1;
        int n = n0 + row; if (n >= N_NODES_C) n = N_NODES_C - 1;
        const float4* ap = (const float4*)(agg + (size_t)n * 64 + hf * 32);
        int r7 = row & 7;
        #pragma unroll
        for (int q = 0; q < 4; ++q) {
            float4 x = ap[2 * q], y = ap[2 * q + 1];
            uint4 pk = { pack2(x.x * invZ, x.y * invZ), pack2(x.z * invZ, x.w * invZ),
                         pack2(y.x * invZ, y.y * invZ), pack2(y.z * invZ, y.w * invZ) };
            int chunk = hf * 4 + q;
            *(uint4*)(Ua + row * 64 + ((chunk ^ r7) << 3)) = pk;
        }
    }
    __syncthreads();

    const int lane = tid & 63, w = tid >> 6;
    const int lr = lane & 31, hi = lane >> 5, kh = hi * 8;
    const int row_a = w * 32 + lr, r7 = lr & 7;

    f32x16 c0, c1;
    #pragma unroll
    for (int j = 0; j < 16; ++j) { c0[j] = 0.f; c1[j] = 0.f; }
    const ushort_t* un = Un + row_a * 64;
    const ushort_t* ua = Ua + row_a * 64;
    const ushort_t* w10 = Wu + lr * 136 + kh;
    const ushort_t* w11 = Wu + (32 + lr) * 136 + kh;
    #pragma unroll
    for (int kk = 0; kk < 4; ++kk) {
        bf16x8 a = *(const bf16x8*)(un + (((2*kk + hi) ^ r7) << 3));
        c0 = __builtin_amdgcn_mfma_f32_32x32x16_bf16(a, *(const bf16x8*)(w10 + kk*16), c0, 0,0,0);
        c1 = __builtin_amdgcn_mfma_f32_32x32x16_bf16(a, *(const bf16x8*)(w11 + kk*16), c1, 0,0,0);
    }
    #pragma unroll
    for (int kk = 4; kk < 8; ++kk) {
        bf16x8 a = *(const bf16x8*)(ua + (((2*kk - 8 + hi) ^ r7) << 3));
        c0 = __builtin_amdgcn_mfma_f32_32x32x16_bf16(a, *(const bf16x8*)(w10 + kk*16), c0, 0,0,0);
        c1 = __builtin_amdgcn_mfma_f32_32x32x16_bf16(a, *(const bf16x8*)(w11 + kk*16), c1, 0,0,0);
    }
    const float bb0 = bu1[lr], bb1 = bu1[32 + lr];
    #pragma unroll
    for (int t = 0; t < 16; ++t) {
        int r = (t & 3) + 8 * (t >> 2) + 4 * hi;
        int g = (w * 32 + r) * 72;
        H2[g + lr]      = f2bf(swish_(c0[t] + bb0));
        H2[g + 32 + lr] = f2bf(swish_(c1[t] + bb1));
    }
    f32x16 d0, d1;
    #pragma unroll
    for (int j = 0; j < 16; ++j) { d0[j] = 0.f; d1[j] = 0.f; }
    const ushort_t* hp = H2 + row_a * 72 + kh;
    const ushort_t* w20 = Wu + 8704 + lr * 72 + kh;
    const ushort_t* w21 = Wu + 8704 + (32 + lr) * 72 + kh;
    #pragma unroll
    for (int kk = 0; kk < 4; ++kk) {
        bf16x8 a = *(const bf16x8*)(hp + kk * 16);
        d0 = __builtin_amdgcn_mfma_f32_32x32x16_bf16(a, *(const bf16x8*)(w20 + kk*16), d0, 0,0,0);
        d1 = __builtin_amdgcn_mfma_f32_32x32x16_bf16(a, *(const bf16x8*)(w21 + kk*16), d1, 0,0,0);
    }
    const float ob0 = bu2[lr], ob1 = bu2[32 + lr];
    #pragma unroll
    for (int t = 0; t < 16; ++t) {
        int r = (t & 3) + 8 * (t >> 2) + 4 * hi;
        int g = n0 + w * 32 + r;
        if (g < N_NODES_C) {
            out[(size_t)g * 64 + lr]      = d0[t] + ob0;
            out[(size_t)g * 64 + 32 + lr] = d1[t] + ob1;
        }
    }
}

extern "C" void kernel_launch(void* const* d_in, const int* in_sizes, int n_in,
                              void* d_out, int out_size, void* d_ws, size_t ws_size,
                              hipStream_t stream)
{
    const float* node      = (const float*)d_in[0];
    const float* edgef     = (const float*)d_in[1];
    const int*   senders   = (const int*)d_in[2];
    const int*   receivers = (const int*)d_in[3];
    const float* W1  = (const float*)d_in[4];
    const float* b1  = (const float*)d_in[5];
    const float* W2  = (const float*)d_in[6];
    const float* b2  = (const float*)d_in[7];
    const float* Wa1 = (const float*)d_in[8];
    const float* ba1 = (const float*)d_in[9];
    const float* Wa2 = (const float*)d_in[10];
    const float* ba2 = (const float*)d_in[11];
    const float* Wu1 = (const float*)d_in[12];
    const float* bu1 = (const float*)d_in[13];
    const float* Wu2 = (const float*)d_in[14];
    const float* bu2 = (const float*)d_in[15];
    float* out = (float*)d_out;

    char* ws = (char*)d_ws;
    float*    expsum  = (float*)ws;
    float*    agg     = (float*)(ws + AGG_OFF);
    ushort_t* node_bf = (ushort_t*)(ws + NB_OFF);
    ushort_t* wimg    = (ushort_t*)(ws + WIMG_OFF);
    ushort_t* wuimg   = (ushort_t*)(ws + WUIMG_OFF);

    ushort_t* wm   = wimg;
    ushort_t* wa   = wimg + 10752;
    ushort_t* w2t  = wimg + 21504;
    ushort_t* wu1t = wuimg;
    ushort_t* wu2t = wuimg + 8704;

    // zero expsum + agg
    hipMemsetAsync(ws, 0, AGG_OFF + (size_t)N_NODES_C * 64 * 4, stream);

    k_prep_node<<<(N_NODES_C * 64 / 8 + 255) / 256, 256, 0, stream>>>(node, node_bf);
    k_prep_w<<<77, 256, 0, stream>>>(W1, Wa1, W2, Wu1, Wu2, wm, wa, w2t, wu1t, wu2t);
    k_edge<<<N_EDGES_C / 256, 512, 0, stream>>>(node_bf, edgef, senders, receivers,
                                                wimg, b1, ba1, Wa2, ba2, b2, expsum, agg);
    k_upd<<<(N_NODES_C + 127) / 128, 256, 0, stream>>>(node_bf, agg, wuimg,
                                                       bu1, bu2, expsum, out);
}